// Round 9
// baseline (1394.463 us; speedup 1.0000x reference)
//
#include <hip/hip_runtime.h>
#include <hip/hip_bf16.h>
#include <cstdint>
#include <cstddef>

#define B_ 128
#define D_ 1024
#define GEN_V_ 50000
#define OUT_V_ 50257
#define S_ 512

#define NTILE 128
#define NBLK 391           // ceil(GEN_V/128)
#define NPAD (NBLK * 128)  // 50048 staged n-columns
#define CAP 8              // bucket capacity for inverted index (Poisson lambda~1)

// Wstage: [nblk][n_in(128)][k(1024)] bf16 -> per gemm-block contiguous 256KB
#define WSTAGE_BLK_U16 (128 * 1024)   // 131072

typedef __attribute__((ext_vector_type(8))) short bf16x8;
typedef __attribute__((ext_vector_type(4))) float f32x4;

__device__ __forceinline__ unsigned short f2bf(float f) {
  unsigned u = __float_as_uint(f);
  u += 0x7fffu + ((u >> 16) & 1u);   // RNE
  return (unsigned short)(u >> 16);
}

// ---------------- prep_x: x fp32 [128][1024] -> bf16 same layout ----------------
__global__ void prep_x_kernel(const float* __restrict__ x, unsigned short* __restrict__ xs) {
  int i4 = blockIdx.x * 256 + threadIdx.x;      // 32768 float4s total
  float4 v = ((const float4*)x)[i4];
  ushort4 h;
  h.x = f2bf(v.x); h.y = f2bf(v.y); h.z = f2bf(v.z); h.w = f2bf(v.w);
  ((ushort4*)xs)[i4] = h;
}

// ---------------- prep_w: W fp32 [k][GEN_V] -> bf16 Wstage[nblk][n][k] ----------
// Reads full k-rows in 4KB coalesced chunks (the ONLY HBM-efficient way to touch W).
// Writes 2B-scattered at 2KB stride, but: one block covers exactly ONE 32-k group,
// so each 64B dest line (k0..k0+31 of one n) is filled by 32 L2-hit partial writes
// over a 64KB rolling window (1024-n chunk) -> HBM sees one 64B eviction per line.
// Grid: 32 k-groups x 8 n-spans (span=6256), 256 threads.
__global__ void prep_w_kernel(const float* __restrict__ W, unsigned short* __restrict__ ws) {
  int g = blockIdx.x;        // k-group: rows [g*32, g*32+32)
  int s = blockIdx.y;        // n-span:  [s*6256, (s+1)*6256)
  int tid = threadIdx.x;     // 256
  for (int c = 0; c < 7; ++c) {                  // 1024-n chunks (7th partial: 112)
    int width = 6256 - c * 1024; if (width > 1024) width = 1024;
    int n4 = s * 6256 + c * 1024 + tid * 4;
    bool act = (tid * 4 < width);
    if (!act) continue;
    for (int k = 0; k < 32; ++k) {
      int kabs = g * 32 + k;
      float4 v = make_float4(0.f, 0.f, 0.f, 0.f);
      if (n4 < GEN_V_) v = *(const float4*)(W + (size_t)kabs * GEN_V_ + n4);
#pragma unroll
      for (int e = 0; e < 4; ++e) {
        int n = n4 + e;
        float f = (e == 0) ? v.x : (e == 1) ? v.y : (e == 2) ? v.z : v.w;
        ws[(size_t)(n >> 7) * WSTAGE_BLK_U16 + (size_t)(n & 127) * 1024 + kabs] = f2bf(f);
      }
    }
  }
}

// ---------------- GEMM + fused exp + row partial sums -----------------------------
// elog[b][v] = exp(x@W_gen + b_gen);  rowpart[row][blk] = sum over this block's cols.
// Inputs pre-converted bf16 in fragment-exact layout: B-frag = 16B contiguous in
// Wstage (block slab = contiguous 256KB, L3-hot from prep_w); A-frag = 16B in xstage
// (L2-hot, 256KB). NO LDS, NO barriers, ZERO VALU in the K-loop: per half-step
// 6 x 16B immediate-offset loads + 8 MFMA, pure dataflow vmcnt.
// Block: 512 threads (8 waves, 2(M)x4(N)), tile M=128 x N=128, wave 64x32, acc[4][2].
__global__ __launch_bounds__(512, 4) void gemm_kernel(
    const unsigned short* __restrict__ xs, const unsigned short* __restrict__ ws,
    const float* __restrict__ bgen, float* __restrict__ elog,
    float* __restrict__ rowpart) {
  __shared__ float srow[B_];
  int tid = threadIdx.x;
  int lane = tid & 63;
  int wv = tid >> 6;            // 0..7
  int wm = wv & 1;              // m half (64)
  int wn = wv >> 1;             // n quarter (32 cols)
  int nbase = blockIdx.x * NTILE;
  int l15 = lane & 15;
  int quad = lane >> 4;
  int koff0 = quad * 8;

  f32x4 acc[4][2];
#pragma unroll
  for (int i = 0; i < 4; i++)
#pragma unroll
    for (int j = 0; j < 2; j++) acc[i][j] = (f32x4){0.f, 0.f, 0.f, 0.f};

  // fragment base pointers (all 16B-aligned; k advances via immediate offsets)
  int nin0 = wn * 32 + l15;          // 0..127, always inside slab (slab covers NPAD)
  const unsigned short* bp0 = ws + (size_t)blockIdx.x * WSTAGE_BLK_U16 + (size_t)nin0 * 1024 + koff0;
  const unsigned short* bp1 = bp0 + 16 * 1024;
  const unsigned short* ap0 = xs + (size_t)(wm * 64 + 0 * 16 + l15) * 1024 + koff0;
  const unsigned short* ap1 = xs + (size_t)(wm * 64 + 1 * 16 + l15) * 1024 + koff0;
  const unsigned short* ap2 = xs + (size_t)(wm * 64 + 2 * 16 + l15) * 1024 + koff0;
  const unsigned short* ap3 = xs + (size_t)(wm * 64 + 3 * 16 + l15) * 1024 + koff0;

  for (int t = 0; t < 4; ++t) {      // 4 groups x 8 half-steps (imm offsets 0..448B)
#pragma unroll
    for (int h = 0; h < 8; ++h) {
      int ko = h * 32;               // u16 offset: 32 k per half-step
      bf16x8 b0 = *(const bf16x8*)(bp0 + ko);
      bf16x8 b1 = *(const bf16x8*)(bp1 + ko);
      bf16x8 a0 = *(const bf16x8*)(ap0 + ko);
      bf16x8 a1 = *(const bf16x8*)(ap1 + ko);
      bf16x8 a2 = *(const bf16x8*)(ap2 + ko);
      bf16x8 a3 = *(const bf16x8*)(ap3 + ko);
      acc[0][0] = __builtin_amdgcn_mfma_f32_16x16x32_bf16(a0, b0, acc[0][0], 0, 0, 0);
      acc[0][1] = __builtin_amdgcn_mfma_f32_16x16x32_bf16(a0, b1, acc[0][1], 0, 0, 0);
      acc[1][0] = __builtin_amdgcn_mfma_f32_16x16x32_bf16(a1, b0, acc[1][0], 0, 0, 0);
      acc[1][1] = __builtin_amdgcn_mfma_f32_16x16x32_bf16(a1, b1, acc[1][1], 0, 0, 0);
      acc[2][0] = __builtin_amdgcn_mfma_f32_16x16x32_bf16(a2, b0, acc[2][0], 0, 0, 0);
      acc[2][1] = __builtin_amdgcn_mfma_f32_16x16x32_bf16(a2, b1, acc[2][1], 0, 0, 0);
      acc[3][0] = __builtin_amdgcn_mfma_f32_16x16x32_bf16(a3, b0, acc[3][0], 0, 0, 0);
      acc[3][1] = __builtin_amdgcn_mfma_f32_16x16x32_bf16(a3, b1, acc[3][1], 0, 0, 0);
    }
    bp0 += 256; bp1 += 256;          // next 8 half-steps (256 u16 = 512B)
    ap0 += 256; ap1 += 256; ap2 += 256; ap3 += 256;
  }

  // ---- epilogue: e = exp(acc + bias); store elog; per-row partial sums ----
  if (tid < B_) srow[tid] = 0.f;
  __syncthreads();
  int rquad = quad * 4;
#pragma unroll
  for (int nt = 0; nt < 2; nt++) {
    int cg = nbase + wn * 32 + nt * 16 + l15;
    bool cv = cg < GEN_V_;
    float bgv = cv ? bgen[cg] : 0.f;
#pragma unroll
    for (int mt = 0; mt < 4; mt++) {
      int rb = wm * 64 + mt * 16 + rquad;
#pragma unroll
      for (int r = 0; r < 4; r++) {
        float e = __expf(acc[mt][nt][r] + bgv);   // logits in ±~5: no max-sub needed
        float contrib = cv ? e : 0.f;
        if (cv) elog[(size_t)(rb + r) * GEN_V_ + cg] = e;
        // reduce across the 16 lanes sharing this row (stays within quad)
#pragma unroll
        for (int o = 1; o < 16; o <<= 1) contrib += __shfl_xor(contrib, o);
        if (l15 == 0) atomicAdd(&srow[rb + r], contrib);
      }
    }
  }
  __syncthreads();
  if (tid < B_) rowpart[(size_t)tid * NBLK + blockIdx.x] = srow[tid];
}

// ------------- inverted index of g2o: fixed-cap buckets + overflow list -------------
__global__ void build_index_kernel(const int* __restrict__ g2o, int* __restrict__ cnt,
                                   int* __restrict__ vlist, int* __restrict__ novf,
                                   int* __restrict__ ovf) {
  int v = blockIdx.x * 256 + threadIdx.x;
  if (v < GEN_V_) {
    int o = g2o[v];
    int slot = atomicAdd(&cnt[o], 1);
    if (slot < CAP) {
      vlist[o * CAP + slot] = v;
    } else {
      int i = atomicAdd(novf, 1);
      ovf[2 * i] = o;
      ovf[2 * i + 1] = v;
    }
  }
}

// ------------- rowsum + gate fused: rowscale[b] = sigmoid(x·Wg+bg) / sum_b ---------
__global__ void rowsum_gate_kernel(const float* __restrict__ rowpart,
                                   const float* __restrict__ x, const float* __restrict__ Wg,
                                   const float* __restrict__ bg,
                                   float* __restrict__ interp, float* __restrict__ rowscale) {
  int b = blockIdx.x, t = threadIdx.x;  // 128 blocks x 256
  const float* rp = rowpart + (size_t)b * NBLK;
  float s = 0.f;
  for (int i = t; i < NBLK; i += 256) s += rp[i];
  // gate dot-product: D/4 = 256 float4 chunks, exactly one per thread
  const float4* xr = (const float4*)(x + (size_t)b * D_);
  const float4* wr = (const float4*)Wg;
  float4 xv = xr[t], wv = wr[t];
  float g = xv.x * wv.x + xv.y * wv.y + xv.z * wv.z + xv.w * wv.w;
  for (int o = 32; o > 0; o >>= 1) {
    s += __shfl_down(s, o);
    g += __shfl_down(g, o);
  }
  __shared__ float reds[4], redg[4];
  int lane = t & 63, w = t >> 6;
  if (lane == 0) { reds[w] = s; redg[w] = g; }
  __syncthreads();
  if (t == 0) {
    float tot = redg[0] + redg[1] + redg[2] + redg[3] + bg[0];
    float itp = 1.f / (1.f + __expf(-tot));
    float sum = reds[0] + reds[1] + reds[2] + reds[3];
    interp[b] = itp;
    rowscale[b] = itp / sum;
  }
}

// -------- gen gather: out[b,o] = rowscale_b * sum_{v in bucket(o)} elog[b,v] --------
// XCD b-affinity: block id -> b = (id&7)*16 + ((id>>3)&15), oc = id>>7.
#define GATHER_NB (128 * 197)   // 197 = ceil(OUT_V/256) o-chunks x 128 b
__global__ void gather_gen_kernel(const float* __restrict__ elog, const int* __restrict__ cnt,
                                  const int* __restrict__ vlist,
                                  const float* __restrict__ rowscale, float* __restrict__ out) {
  int id = blockIdx.x;
  int b = (id & 7) * 16 + ((id >> 3) & 15);
  int o = (id >> 7) * 256 + threadIdx.x;
  if (o < OUT_V_) {
    int c = cnt[o];
    if (c > CAP) c = CAP;
    const float* lrow = elog + (size_t)b * GEN_V_;
    const int* vl = vlist + (size_t)o * CAP;
    float s = 0.f;
    for (int j = 0; j < c; j++) s += lrow[vl[j]];
    out[(size_t)b * OUT_V_ + o] = s * rowscale[b];
  }
}

// ---------------- overflow cleanup (normally novf==0): atomic adds ------------------
__global__ void ovf_kernel(const int* __restrict__ novf, const int* __restrict__ ovf,
                           const float* __restrict__ elog, const float* __restrict__ rowscale,
                           float* __restrict__ out) {
  int n = novf[0];
  if (n == 0) return;
  int total = n * B_;
  for (int i = blockIdx.x * 256 + threadIdx.x; i < total; i += gridDim.x * 256) {
    int e = i >> 7;          // entry
    int b = i & 127;         // row
    int o = ovf[2 * e];
    int v = ovf[2 * e + 1];
    atomicAdd(&out[(size_t)b * OUT_V_ + o], rowscale[b] * elog[(size_t)b * GEN_V_ + v]);
  }
}

// ---------------- ptr scatter: out[b, i2o[ctx[b,s]]] += (1-interp_b) * alphas[b,s] --
__global__ void scatter_ptr_kernel(const float* __restrict__ alphas, const int* __restrict__ ctx,
                                   const int* __restrict__ i2o, const float* __restrict__ interp,
                                   float* __restrict__ out) {
  int b = blockIdx.x, s = threadIdx.x;  // 512 threads
  float w = 1.f - interp[b];
  int o = i2o[ctx[b * S_ + s]];
  atomicAdd(&out[(size_t)b * OUT_V_ + o], w * alphas[b * S_ + s]);
}

extern "C" void kernel_launch(void* const* d_in, const int* in_sizes, int n_in,
                              void* d_out, int out_size, void* d_ws, size_t ws_size,
                              hipStream_t stream) {
  const float* x      = (const float*)d_in[0];
  const float* alphas = (const float*)d_in[1];
  const float* Wg     = (const float*)d_in[2];
  const float* bg     = (const float*)d_in[3];
  const float* Wgen   = (const float*)d_in[4];
  const float* bgen   = (const float*)d_in[5];
  const int*   ctx    = (const int*)d_in[6];
  const int*   g2o    = (const int*)d_in[7];
  const int*   i2o    = (const int*)d_in[8];
  float* out = (float*)d_out;

  // workspace layout (Wstage/xstage FIRST for 16B alignment):
  // Wstage u16[391*131072] | xstage u16[131072] | elog f[128*50000] | interp[128]
  // | rowscale[128] | rowpart[128*NBLK] | cnt[OUT_V] | novf[1] | vlist[OUT_V*CAP]
  // | ovf[2*GEN_V]
  unsigned short* Wstage = (unsigned short*)d_ws;
  unsigned short* xstage = Wstage + (size_t)NBLK * WSTAGE_BLK_U16;
  float* elog      = (float*)(xstage + (size_t)B_ * D_);
  float* interp    = elog + (size_t)B_ * GEN_V_;
  float* rowscale  = interp + B_;
  float* rowpart   = rowscale + B_;
  int*   cnt       = (int*)(rowpart + (size_t)B_ * NBLK);
  int*   novf      = cnt + OUT_V_;
  int*   vlist     = novf + 1;
  int*   ovf       = vlist + (size_t)OUT_V_ * CAP;

  hipMemsetAsync(cnt, 0, (OUT_V_ + 1) * sizeof(int), stream);

  prep_x_kernel<<<128, 256, 0, stream>>>(x, xstage);
  prep_w_kernel<<<dim3(32, 8), 256, 0, stream>>>(Wgen, Wstage);
  build_index_kernel<<<(GEN_V_ + 255) / 256, 256, 0, stream>>>(g2o, cnt, vlist, novf, ovf);
  gemm_kernel<<<NBLK, 512, 0, stream>>>(xstage, Wstage, bgen, elog, rowpart);
  rowsum_gate_kernel<<<B_, 256, 0, stream>>>(rowpart, x, Wg, bg, interp, rowscale);
  gather_gen_kernel<<<GATHER_NB, 256, 0, stream>>>(elog, cnt, vlist, rowscale, out);
  ovf_kernel<<<64, 256, 0, stream>>>(novf, ovf, elog, rowscale, out);
  scatter_ptr_kernel<<<B_, S_, 0, stream>>>(alphas, ctx, i2o, interp, out);
}

// Round 10
// 502.073 us; speedup vs baseline: 2.7774x; 2.7774x over previous
//
#include <hip/hip_runtime.h>
#include <hip/hip_bf16.h>
#include <cstdint>
#include <cstddef>

#define B_ 128
#define D_ 1024
#define GEN_V_ 50000
#define OUT_V_ 50257
#define S_ 512

#define NTILE 128
#define NBLK 391           // ceil(GEN_V/128)
#define NPAD (NBLK * 128)  // 50048 staged n-columns
#define CAP 8              // bucket capacity for inverted index (Poisson lambda~1)

// Wstage: bf16 [n][k=1024]; addr(n,k) = n*1024 + k  (per-gemm-block slab = 256KB)
#define WSTAGE_BLK_U16 (128 * 1024)   // 131072

typedef __attribute__((ext_vector_type(8))) short bf16x8;
typedef __attribute__((ext_vector_type(4))) float f32x4;

__device__ __forceinline__ unsigned short f2bf(float f) {
  unsigned u = __float_as_uint(f);
  u += 0x7fffu + ((u >> 16) & 1u);   // RNE
  return (unsigned short)(u >> 16);
}

// ---------------- prep_x: x fp32 [128][1024] -> bf16 same layout ----------------
__global__ void prep_x_kernel(const float* __restrict__ x, unsigned short* __restrict__ xs) {
  int i4 = blockIdx.x * 256 + threadIdx.x;      // 32768 float4s total
  float4 v = ((const float4*)x)[i4];
  ushort4 h;
  h.x = f2bf(v.x); h.y = f2bf(v.y); h.z = f2bf(v.z); h.w = f2bf(v.w);
  ((ushort4*)xs)[i4] = h;
}

// ---------------- prep_w: W fp32 [k][GEN_V] -> bf16 Wstage[n][k] (LDS transpose) ---
// R9 lesson: 2B scattered stores do NOT combine in L2 (WRITE_SIZE 18x dest). Here
// every HBM write is a FULL 64B line from ONE instruction-group: phase 2 maps lanes
// to (n_local = e>>3, kq = e&7) so 8 lanes x uint2(8B) = one contiguous 64B line,
// 8 full lines per store instruction. Phase 1 reads are lane-consecutive-n (1KB
// coalesced per k-row). LDS [256][17] dwords: stride 17 (coprime 32) -> conflict-free.
// Grid: (32 k-groups) x (196 n-tiles), 256 threads.
__global__ void prep_w_kernel(const float* __restrict__ W, unsigned short* __restrict__ ws) {
  __shared__ unsigned int lds[256][17];   // [n_local][k-pair] (2 bf16 per dword)
  int g = blockIdx.x;          // k-group: rows [g*32, g*32+32)
  int nt = blockIdx.y;         // n-tile: [nt*256, nt*256+256)
  int t = threadIdx.x;         // 256
  int n = nt * 256 + t;
  int k0 = g * 32;
  // phase 1: 16 k-pairs, coalesced reads, pack 2xbf16 -> dword into LDS
#pragma unroll 4
  for (int kp = 0; kp < 16; ++kp) {
    float lo = 0.f, hi = 0.f;
    if (n < GEN_V_) {
      lo = W[(size_t)(k0 + 2 * kp) * GEN_V_ + n];
      hi = W[(size_t)(k0 + 2 * kp + 1) * GEN_V_ + n];
    }
    lds[t][kp] = (unsigned)f2bf(lo) | ((unsigned)f2bf(hi) << 16);
  }
  __syncthreads();
  // phase 2: 8 passes; lane -> (n_local, kq); each 8-lane group writes one 64B line
#pragma unroll
  for (int p = 0; p < 8; ++p) {
    int e = p * 256 + t;
    int nl = e >> 3;           // 0..255
    int kq = e & 7;            // k-offset kq*4 within the 32-k group
    int ng = nt * 256 + nl;
    if (ng < NPAD) {
      uint2 v;
      v.x = lds[nl][kq * 2];
      v.y = lds[nl][kq * 2 + 1];
      *(uint2*)(ws + (size_t)ng * 1024 + k0 + kq * 4) = v;
    }
  }
}

// ---------------- GEMM + fused exp + row partial sums -----------------------------
// elog[b][v] = exp(x@W_gen + b_gen);  rowpart[row][blk] = sum over this block's cols.
// Inputs pre-converted bf16 in fragment-exact layout: B-frag = 16B contiguous in
// Wstage (block slab = contiguous 256KB); A-frag = 16B in xstage (L2-hot, 256KB).
// NO LDS, NO barriers, ZERO VALU in the K-loop: per half-step 6 x 16B
// immediate-offset loads + 8 MFMA, pure dataflow vmcnt.
// Block: 512 threads (8 waves, 2(M)x4(N)), tile M=128 x N=128, wave 64x32, acc[4][2].
__global__ __launch_bounds__(512, 4) void gemm_kernel(
    const unsigned short* __restrict__ xs, const unsigned short* __restrict__ ws,
    const float* __restrict__ bgen, float* __restrict__ elog,
    float* __restrict__ rowpart) {
  __shared__ float srow[B_];
  int tid = threadIdx.x;
  int lane = tid & 63;
  int wv = tid >> 6;            // 0..7
  int wm = wv & 1;              // m half (64)
  int wn = wv >> 1;             // n quarter (32 cols)
  int nbase = blockIdx.x * NTILE;
  int l15 = lane & 15;
  int quad = lane >> 4;
  int koff0 = quad * 8;

  f32x4 acc[4][2];
#pragma unroll
  for (int i = 0; i < 4; i++)
#pragma unroll
    for (int j = 0; j < 2; j++) acc[i][j] = (f32x4){0.f, 0.f, 0.f, 0.f};

  // fragment base pointers (all 16B-aligned; k advances via immediate offsets)
  int nin0 = wn * 32 + l15;          // 0..127 within slab
  const unsigned short* bp0 = ws + (size_t)blockIdx.x * WSTAGE_BLK_U16 + (size_t)nin0 * 1024 + koff0;
  const unsigned short* bp1 = bp0 + 16 * 1024;
  const unsigned short* ap0 = xs + (size_t)(wm * 64 + 0 * 16 + l15) * 1024 + koff0;
  const unsigned short* ap1 = xs + (size_t)(wm * 64 + 1 * 16 + l15) * 1024 + koff0;
  const unsigned short* ap2 = xs + (size_t)(wm * 64 + 2 * 16 + l15) * 1024 + koff0;
  const unsigned short* ap3 = xs + (size_t)(wm * 64 + 3 * 16 + l15) * 1024 + koff0;

  for (int t = 0; t < 4; ++t) {      // 4 groups x 8 half-steps (imm offsets 0..448B)
#pragma unroll
    for (int h = 0; h < 8; ++h) {
      int ko = h * 32;               // u16 offset: 32 k per half-step
      bf16x8 b0 = *(const bf16x8*)(bp0 + ko);
      bf16x8 b1 = *(const bf16x8*)(bp1 + ko);
      bf16x8 a0 = *(const bf16x8*)(ap0 + ko);
      bf16x8 a1 = *(const bf16x8*)(ap1 + ko);
      bf16x8 a2 = *(const bf16x8*)(ap2 + ko);
      bf16x8 a3 = *(const bf16x8*)(ap3 + ko);
      acc[0][0] = __builtin_amdgcn_mfma_f32_16x16x32_bf16(a0, b0, acc[0][0], 0, 0, 0);
      acc[0][1] = __builtin_amdgcn_mfma_f32_16x16x32_bf16(a0, b1, acc[0][1], 0, 0, 0);
      acc[1][0] = __builtin_amdgcn_mfma_f32_16x16x32_bf16(a1, b0, acc[1][0], 0, 0, 0);
      acc[1][1] = __builtin_amdgcn_mfma_f32_16x16x32_bf16(a1, b1, acc[1][1], 0, 0, 0);
      acc[2][0] = __builtin_amdgcn_mfma_f32_16x16x32_bf16(a2, b0, acc[2][0], 0, 0, 0);
      acc[2][1] = __builtin_amdgcn_mfma_f32_16x16x32_bf16(a2, b1, acc[2][1], 0, 0, 0);
      acc[3][0] = __builtin_amdgcn_mfma_f32_16x16x32_bf16(a3, b0, acc[3][0], 0, 0, 0);
      acc[3][1] = __builtin_amdgcn_mfma_f32_16x16x32_bf16(a3, b1, acc[3][1], 0, 0, 0);
    }
    bp0 += 256; bp1 += 256;          // next 8 half-steps (256 u16 = 512B)
    ap0 += 256; ap1 += 256; ap2 += 256; ap3 += 256;
  }

  // ---- epilogue: e = exp(acc + bias); store elog; per-row partial sums ----
  if (tid < B_) srow[tid] = 0.f;
  __syncthreads();
  int rquad = quad * 4;
#pragma unroll
  for (int nt = 0; nt < 2; nt++) {
    int cg = nbase + wn * 32 + nt * 16 + l15;
    bool cv = cg < GEN_V_;
    float bgv = cv ? bgen[cg] : 0.f;
#pragma unroll
    for (int mt = 0; mt < 4; mt++) {
      int rb = wm * 64 + mt * 16 + rquad;
#pragma unroll
      for (int r = 0; r < 4; r++) {
        float e = __expf(acc[mt][nt][r] + bgv);   // logits in ±~5: no max-sub needed
        float contrib = cv ? e : 0.f;
        if (cv) elog[(size_t)(rb + r) * GEN_V_ + cg] = e;
        // reduce across the 16 lanes sharing this row (stays within quad)
#pragma unroll
        for (int o = 1; o < 16; o <<= 1) contrib += __shfl_xor(contrib, o);
        if (l15 == 0) atomicAdd(&srow[rb + r], contrib);
      }
    }
  }
  __syncthreads();
  if (tid < B_) rowpart[(size_t)tid * NBLK + blockIdx.x] = srow[tid];
}

// ------------- inverted index of g2o: fixed-cap buckets + overflow list -------------
__global__ void build_index_kernel(const int* __restrict__ g2o, int* __restrict__ cnt,
                                   int* __restrict__ vlist, int* __restrict__ novf,
                                   int* __restrict__ ovf) {
  int v = blockIdx.x * 256 + threadIdx.x;
  if (v < GEN_V_) {
    int o = g2o[v];
    int slot = atomicAdd(&cnt[o], 1);
    if (slot < CAP) {
      vlist[o * CAP + slot] = v;
    } else {
      int i = atomicAdd(novf, 1);
      ovf[2 * i] = o;
      ovf[2 * i + 1] = v;
    }
  }
}

// ------------- rowsum + gate fused: rowscale[b] = sigmoid(x·Wg+bg) / sum_b ---------
__global__ void rowsum_gate_kernel(const float* __restrict__ rowpart,
                                   const float* __restrict__ x, const float* __restrict__ Wg,
                                   const float* __restrict__ bg,
                                   float* __restrict__ interp, float* __restrict__ rowscale) {
  int b = blockIdx.x, t = threadIdx.x;  // 128 blocks x 256
  const float* rp = rowpart + (size_t)b * NBLK;
  float s = 0.f;
  for (int i = t; i < NBLK; i += 256) s += rp[i];
  // gate dot-product: D/4 = 256 float4 chunks, exactly one per thread
  const float4* xr = (const float4*)(x + (size_t)b * D_);
  const float4* wr = (const float4*)Wg;
  float4 xv = xr[t], wv = wr[t];
  float g = xv.x * wv.x + xv.y * wv.y + xv.z * wv.z + xv.w * wv.w;
  for (int o = 32; o > 0; o >>= 1) {
    s += __shfl_down(s, o);
    g += __shfl_down(g, o);
  }
  __shared__ float reds[4], redg[4];
  int lane = t & 63, w = t >> 6;
  if (lane == 0) { reds[w] = s; redg[w] = g; }
  __syncthreads();
  if (t == 0) {
    float tot = redg[0] + redg[1] + redg[2] + redg[3] + bg[0];
    float itp = 1.f / (1.f + __expf(-tot));
    float sum = reds[0] + reds[1] + reds[2] + reds[3];
    interp[b] = itp;
    rowscale[b] = itp / sum;
  }
}

// -------- gen gather: out[b,o] = rowscale_b * sum_{v in bucket(o)} elog[b,v] --------
// XCD b-affinity: block id -> b = (id&7)*16 + ((id>>3)&15), oc = id>>7.
#define GATHER_NB (128 * 197)   // 197 = ceil(OUT_V/256) o-chunks x 128 b
__global__ void gather_gen_kernel(const float* __restrict__ elog, const int* __restrict__ cnt,
                                  const int* __restrict__ vlist,
                                  const float* __restrict__ rowscale, float* __restrict__ out) {
  int id = blockIdx.x;
  int b = (id & 7) * 16 + ((id >> 3) & 15);
  int o = (id >> 7) * 256 + threadIdx.x;
  if (o < OUT_V_) {
    int c = cnt[o];
    if (c > CAP) c = CAP;
    const float* lrow = elog + (size_t)b * GEN_V_;
    const int* vl = vlist + (size_t)o * CAP;
    float s = 0.f;
    for (int j = 0; j < c; j++) s += lrow[vl[j]];
    out[(size_t)b * OUT_V_ + o] = s * rowscale[b];
  }
}

// ---------------- overflow cleanup (normally novf==0): atomic adds ------------------
__global__ void ovf_kernel(const int* __restrict__ novf, const int* __restrict__ ovf,
                           const float* __restrict__ elog, const float* __restrict__ rowscale,
                           float* __restrict__ out) {
  int n = novf[0];
  if (n == 0) return;
  int total = n * B_;
  for (int i = blockIdx.x * 256 + threadIdx.x; i < total; i += gridDim.x * 256) {
    int e = i >> 7;          // entry
    int b = i & 127;         // row
    int o = ovf[2 * e];
    int v = ovf[2 * e + 1];
    atomicAdd(&out[(size_t)b * OUT_V_ + o], rowscale[b] * elog[(size_t)b * GEN_V_ + v]);
  }
}

// ---------------- ptr scatter: out[b, i2o[ctx[b,s]]] += (1-interp_b) * alphas[b,s] --
__global__ void scatter_ptr_kernel(const float* __restrict__ alphas, const int* __restrict__ ctx,
                                   const int* __restrict__ i2o, const float* __restrict__ interp,
                                   float* __restrict__ out) {
  int b = blockIdx.x, s = threadIdx.x;  // 512 threads
  float w = 1.f - interp[b];
  int o = i2o[ctx[b * S_ + s]];
  atomicAdd(&out[(size_t)b * OUT_V_ + o], w * alphas[b * S_ + s]);
}

extern "C" void kernel_launch(void* const* d_in, const int* in_sizes, int n_in,
                              void* d_out, int out_size, void* d_ws, size_t ws_size,
                              hipStream_t stream) {
  const float* x      = (const float*)d_in[0];
  const float* alphas = (const float*)d_in[1];
  const float* Wg     = (const float*)d_in[2];
  const float* bg     = (const float*)d_in[3];
  const float* Wgen   = (const float*)d_in[4];
  const float* bgen   = (const float*)d_in[5];
  const int*   ctx    = (const int*)d_in[6];
  const int*   g2o    = (const int*)d_in[7];
  const int*   i2o    = (const int*)d_in[8];
  float* out = (float*)d_out;

  // workspace layout (Wstage/xstage FIRST for 16B alignment):
  // Wstage u16[391*131072] | xstage u16[131072] | elog f[128*50000] | interp[128]
  // | rowscale[128] | rowpart[128*NBLK] | cnt[OUT_V] | novf[1] | vlist[OUT_V*CAP]
  // | ovf[2*GEN_V]
  unsigned short* Wstage = (unsigned short*)d_ws;
  unsigned short* xstage = Wstage + (size_t)NBLK * WSTAGE_BLK_U16;
  float* elog      = (float*)(xstage + (size_t)B_ * D_);
  float* interp    = elog + (size_t)B_ * GEN_V_;
  float* rowscale  = interp + B_;
  float* rowpart   = rowscale + B_;
  int*   cnt       = (int*)(rowpart + (size_t)B_ * NBLK);
  int*   novf      = cnt + OUT_V_;
  int*   vlist     = novf + 1;
  int*   ovf       = vlist + (size_t)OUT_V_ * CAP;

  hipMemsetAsync(cnt, 0, (OUT_V_ + 1) * sizeof(int), stream);

  prep_x_kernel<<<128, 256, 0, stream>>>(x, xstage);
  prep_w_kernel<<<dim3(32, 196), 256, 0, stream>>>(Wgen, Wstage);
  build_index_kernel<<<(GEN_V_ + 255) / 256, 256, 0, stream>>>(g2o, cnt, vlist, novf, ovf);
  gemm_kernel<<<NBLK, 512, 0, stream>>>(xstage, Wstage, bgen, elog, rowpart);
  rowsum_gate_kernel<<<B_, 256, 0, stream>>>(rowpart, x, Wg, bg, interp, rowscale);
  gather_gen_kernel<<<GATHER_NB, 256, 0, stream>>>(elog, cnt, vlist, rowscale, out);
  ovf_kernel<<<64, 256, 0, stream>>>(novf, ovf, elog, rowscale, out);
  scatter_ptr_kernel<<<B_, S_, 0, stream>>>(alphas, ctx, i2o, interp, out);
}

// Round 11
// 382.882 us; speedup vs baseline: 3.6420x; 1.3113x over previous
//
#include <hip/hip_runtime.h>
#include <hip/hip_bf16.h>
#include <cstdint>
#include <cstddef>

#define B_ 128
#define D_ 1024
#define GEN_V_ 50000
#define OUT_V_ 50257
#define S_ 512

#define NTILE 128
#define NBLK 391         // ceil(GEN_V/128)
#define BK 64
#define NSTEP (D_ / BK)  // 16
#define LD 72            // padded k-stride (shorts); 36-dword row stride
#define CAP 8            // bucket capacity for inverted index (Poisson lambda~1)

typedef __attribute__((ext_vector_type(8))) short bf16x8;
typedef __attribute__((ext_vector_type(8))) unsigned short u16x8;
typedef __attribute__((ext_vector_type(4))) float f32x4;

__device__ __forceinline__ unsigned short f2bf(float f) {
  unsigned u = __float_as_uint(f);
  u += 0x7fffu + ((u >> 16) & 1u);   // RNE
  return (unsigned short)(u >> 16);
}

// ---------------- GEMM + fused exp + row partial sums -----------------------------
// elog[b][v] = exp(x@W_gen + b_gen);  rowpart[row][blk] = sum over this block's cols.
// Block: 512 threads (8 waves, 2(M)x4(N)), tile M=128 x N=128, BK=64.
// R4 configuration (best measured: 382.7 total, gemm ~105): 1-deep register
// prefetch, single LDS buffer, two barriers per step. Deeper pipelines, dbuf,
// direct-load and repacked-bf16 variants all measured neutral-to-worse (R5-R10).
__global__ __launch_bounds__(512, 4) void gemm_kernel(
    const float* __restrict__ x, const float* __restrict__ W,
    const float* __restrict__ bgen, float* __restrict__ elog,
    float* __restrict__ rowpart) {
  __shared__ unsigned short sA[B_][LD];      // [m][k] bf16
  __shared__ unsigned short sB[NTILE][LD];   // [n][k] bf16 (k-packed, conflict-free)
  __shared__ float srow[B_];
  int tid = threadIdx.x;
  int lane = tid & 63;
  int wv = tid >> 6;            // 0..7
  int wm = wv & 1;              // m half (64)
  int wn = wv >> 1;             // n quarter (32 cols)
  int nbase = blockIdx.x * NTILE;
  int l15 = lane & 15;
  int quad = lane >> 4;
  int koff0 = quad * 8;

  f32x4 acc[4][2];
#pragma unroll
  for (int i = 0; i < 4; i++)
#pragma unroll
    for (int j = 0; j < 2; j++) acc[i][j] = (f32x4){0.f, 0.f, 0.f, 0.f};

  // B staging: thread owns (n = tid&127, kc = tid>>7 in 0..3), 16 k's each
  int bn = tid & 127;
  int kc = tid >> 7;
  bool colv = (nbase + bn) < GEN_V_;
  const float* Wcol = W + (size_t)kc * 16 * GEN_V_ + nbase + bn;
  const float4* xg = (const float4*)x;

  // prefetch registers (single set: consumed by WRITE before next LOAD overwrites)
  float wreg[16];
  float4 xreg[4];

  auto LOAD = [&](int k0) {
    const float* Wp = Wcol + (size_t)k0 * GEN_V_;
#pragma unroll
    for (int j = 0; j < 16; j++) wreg[j] = colv ? Wp[(size_t)j * GEN_V_] : 0.f;
    int kb4 = k0 >> 2;
#pragma unroll
    for (int i = 0; i < 4; i++) {
      int q = tid + i * 512;          // 0..2047
      int m = q >> 4, c4 = q & 15;    // 16 float4 per 64-k row
      xreg[i] = xg[(size_t)m * (D_ / 4) + kb4 + c4];
    }
  };
  auto WRITE = [&]() {
#pragma unroll
    for (int i = 0; i < 4; i++) {
      int q = tid + i * 512;
      int m = q >> 4, c4 = q & 15;
      ushort4 h;
      h.x = f2bf(xreg[i].x); h.y = f2bf(xreg[i].y);
      h.z = f2bf(xreg[i].z); h.w = f2bf(xreg[i].w);
      *(ushort4*)&sA[m][c4 * 4] = h;
    }
    u16x8 h0, h1;
#pragma unroll
    for (int j = 0; j < 8; j++) { h0[j] = f2bf(wreg[j]); h1[j] = f2bf(wreg[j + 8]); }
    *(u16x8*)&sB[bn][kc * 16] = h0;      // dword stride 36/row: lanes cover 32 banks
    *(u16x8*)&sB[bn][kc * 16 + 8] = h1;
  };

  // prologue: stage tile 0
  LOAD(0);
  WRITE();
  __syncthreads();

  for (int t = 0; t < NSTEP; ++t) {
    // issue next tile's loads BEFORE compute (latency hides under MFMA phase)
    if (t + 1 < NSTEP) LOAD((t + 1) * BK);
    // ---- MFMA: wave tile 64(M) x 32(N) on LDS tile t ----
#pragma unroll
    for (int ks = 0; ks < BK; ks += 32) {
      int koff = ks + koff0;
      bf16x8 bfr[2];
      bfr[0] = *(const bf16x8*)&sB[wn * 32 + l15][koff];
      bfr[1] = *(const bf16x8*)&sB[wn * 32 + 16 + l15][koff];
      bf16x8 af[4];
#pragma unroll
      for (int mt = 0; mt < 4; mt++)
        af[mt] = *(const bf16x8*)&sA[wm * 64 + mt * 16 + l15][koff];
#pragma unroll
      for (int mt = 0; mt < 4; mt++) {
        acc[mt][0] = __builtin_amdgcn_mfma_f32_16x16x32_bf16(af[mt], bfr[0], acc[mt][0], 0, 0, 0);
        acc[mt][1] = __builtin_amdgcn_mfma_f32_16x16x32_bf16(af[mt], bfr[1], acc[mt][1], 0, 0, 0);
      }
    }
    __syncthreads();                 // all waves done READING tile t
    if (t + 1 < NSTEP) {
      WRITE();                       // waits on loads, converts, ds_writes tile t+1
      __syncthreads();               // tile t+1 visible
    }
  }

  // ---- epilogue: e = exp(acc + bias); store elog; per-row partial sums ----
  if (tid < B_) srow[tid] = 0.f;
  __syncthreads();
  int rquad = quad * 4;
#pragma unroll
  for (int nt = 0; nt < 2; nt++) {
    int cg = nbase + wn * 32 + nt * 16 + l15;
    bool cv = cg < GEN_V_;
    float bgv = cv ? bgen[cg] : 0.f;
#pragma unroll
    for (int mt = 0; mt < 4; mt++) {
      int rb = wm * 64 + mt * 16 + rquad;
#pragma unroll
      for (int r = 0; r < 4; r++) {
        float e = __expf(acc[mt][nt][r] + bgv);   // logits in ±~5: no max-sub needed
        float contrib = cv ? e : 0.f;
        if (cv) elog[(size_t)(rb + r) * GEN_V_ + cg] = e;
        // reduce across the 16 lanes sharing this row (stays within quad)
#pragma unroll
        for (int o = 1; o < 16; o <<= 1) contrib += __shfl_xor(contrib, o);
        if (l15 == 0) atomicAdd(&srow[rb + r], contrib);
      }
    }
  }
  __syncthreads();
  if (tid < B_) rowpart[(size_t)tid * NBLK + blockIdx.x] = srow[tid];
}

// ------------- inverted index of g2o: fixed-cap buckets + overflow list -------------
__global__ void build_index_kernel(const int* __restrict__ g2o, int* __restrict__ cnt,
                                   int* __restrict__ vlist, int* __restrict__ novf,
                                   int* __restrict__ ovf) {
  int v = blockIdx.x * 256 + threadIdx.x;
  if (v < GEN_V_) {
    int o = g2o[v];
    int slot = atomicAdd(&cnt[o], 1);
    if (slot < CAP) {
      vlist[o * CAP + slot] = v;
    } else {
      int i = atomicAdd(novf, 1);
      ovf[2 * i] = o;
      ovf[2 * i + 1] = v;
    }
  }
}

// ------------- rowsum + gate fused: rowscale[b] = sigmoid(x·Wg+bg) / sum_b ---------
__global__ void rowsum_gate_kernel(const float* __restrict__ rowpart,
                                   const float* __restrict__ x, const float* __restrict__ Wg,
                                   const float* __restrict__ bg,
                                   float* __restrict__ interp, float* __restrict__ rowscale) {
  int b = blockIdx.x, t = threadIdx.x;  // 128 blocks x 256
  const float* rp = rowpart + (size_t)b * NBLK;
  float s = 0.f;
  for (int i = t; i < NBLK; i += 256) s += rp[i];
  // gate dot-product: D/4 = 256 float4 chunks, exactly one per thread
  const float4* xr = (const float4*)(x + (size_t)b * D_);
  const float4* wr = (const float4*)Wg;
  float4 xv = xr[t], wv = wr[t];
  float g = xv.x * wv.x + xv.y * wv.y + xv.z * wv.z + xv.w * wv.w;
  for (int o = 32; o > 0; o >>= 1) {
    s += __shfl_down(s, o);
    g += __shfl_down(g, o);
  }
  __shared__ float reds[4], redg[4];
  int lane = t & 63, w = t >> 6;
  if (lane == 0) { reds[w] = s; redg[w] = g; }
  __syncthreads();
  if (t == 0) {
    float tot = redg[0] + redg[1] + redg[2] + redg[3] + bg[0];
    float itp = 1.f / (1.f + __expf(-tot));
    float sum = reds[0] + reds[1] + reds[2] + reds[3];
    interp[b] = itp;
    rowscale[b] = itp / sum;
  }
}

// -------- gen gather: out[b,o] = rowscale_b * sum_{v in bucket(o)} elog[b,v] --------
// XCD b-affinity: block id -> b = (id&7)*16 + ((id>>3)&15), oc = id>>7.
// XCDs take blocks round-robin on id%8, so XCD x owns b in [16x,16x+16): its 16 elog
// rows (3.2 MB) stay resident in that XCD's 4 MB L2 -> no cross-XCD elog re-fetch.
// Each thread now produces TWO outputs (o and o+256): halves block count, amortizes
// launch + cnt/vlist line reuse within the 512-wide o-chunk.
#define GATHER_NB (128 * 99)   // 99 = ceil(OUT_V/512) o-chunks x 128 b
__global__ void gather_gen_kernel(const float* __restrict__ elog, const int* __restrict__ cnt,
                                  const int* __restrict__ vlist,
                                  const float* __restrict__ rowscale, float* __restrict__ out) {
  int id = blockIdx.x;
  int b = (id & 7) * 16 + ((id >> 3) & 15);
  int obase = (id >> 7) * 512 + threadIdx.x;
  float sc = rowscale[b];
  const float* lrow = elog + (size_t)b * GEN_V_;
#pragma unroll
  for (int h = 0; h < 2; ++h) {
    int o = obase + h * 256;
    if (o < OUT_V_) {
      int c = cnt[o];
      if (c > CAP) c = CAP;
      const int* vl = vlist + (size_t)o * CAP;
      float s = 0.f;
      for (int j = 0; j < c; j++) s += lrow[vl[j]];
      out[(size_t)b * OUT_V_ + o] = s * sc;
    }
  }
}

// ---------------- overflow cleanup (normally novf==0): atomic adds ------------------
__global__ void ovf_kernel(const int* __restrict__ novf, const int* __restrict__ ovf,
                           const float* __restrict__ elog, const float* __restrict__ rowscale,
                           float* __restrict__ out) {
  int n = novf[0];
  if (n == 0) return;
  int total = n * B_;
  for (int i = blockIdx.x * 256 + threadIdx.x; i < total; i += gridDim.x * 256) {
    int e = i >> 7;          // entry
    int b = i & 127;         // row
    int o = ovf[2 * e];
    int v = ovf[2 * e + 1];
    atomicAdd(&out[(size_t)b * OUT_V_ + o], rowscale[b] * elog[(size_t)b * GEN_V_ + v]);
  }
}

// ---------------- ptr scatter: out[b, i2o[ctx[b,s]]] += (1-interp_b) * alphas[b,s] --
__global__ void scatter_ptr_kernel(const float* __restrict__ alphas, const int* __restrict__ ctx,
                                   const int* __restrict__ i2o, const float* __restrict__ interp,
                                   float* __restrict__ out) {
  int b = blockIdx.x, s = threadIdx.x;  // 512 threads
  float w = 1.f - interp[b];
  int o = i2o[ctx[b * S_ + s]];
  atomicAdd(&out[(size_t)b * OUT_V_ + o], w * alphas[b * S_ + s]);
}

extern "C" void kernel_launch(void* const* d_in, const int* in_sizes, int n_in,
                              void* d_out, int out_size, void* d_ws, size_t ws_size,
                              hipStream_t stream) {
  const float* x      = (const float*)d_in[0];
  const float* alphas = (const float*)d_in[1];
  const float* Wg     = (const float*)d_in[2];
  const float* bg     = (const float*)d_in[3];
  const float* Wgen   = (const float*)d_in[4];
  const float* bgen   = (const float*)d_in[5];
  const int*   ctx    = (const int*)d_in[6];
  const int*   g2o    = (const int*)d_in[7];
  const int*   i2o    = (const int*)d_in[8];
  float* out = (float*)d_out;

  // workspace layout (4B elems):
  // elog[128*50000] | interp[128] | rowscale[128] | rowpart[128*NBLK]
  // | cnt[OUT_V] | novf[1] | vlist[OUT_V*CAP] | ovf[2*GEN_V]
  float* elog      = (float*)d_ws;
  float* interp    = elog + (size_t)B_ * GEN_V_;
  float* rowscale  = interp + B_;
  float* rowpart   = rowscale + B_;
  int*   cnt       = (int*)(rowpart + (size_t)B_ * NBLK);
  int*   novf      = cnt + OUT_V_;
  int*   vlist     = novf + 1;
  int*   ovf       = vlist + (size_t)OUT_V_ * CAP;

  // zero cnt + novf in one contiguous memset
  hipMemsetAsync(cnt, 0, (OUT_V_ + 1) * sizeof(int), stream);

  build_index_kernel<<<(GEN_V_ + 255) / 256, 256, 0, stream>>>(g2o, cnt, vlist, novf, ovf);
  gemm_kernel<<<NBLK, 512, 0, stream>>>(x, Wgen, bgen, elog, rowpart);
  rowsum_gate_kernel<<<B_, 256, 0, stream>>>(rowpart, x, Wg, bg, interp, rowscale);
  gather_gen_kernel<<<GATHER_NB, 256, 0, stream>>>(elog, cnt, vlist, rowscale, out);
  ovf_kernel<<<64, 256, 0, stream>>>(novf, ovf, elog, rowscale, out);
  scatter_ptr_kernel<<<B_, S_, 0, stream>>>(alphas, ctx, i2o, interp, out);
}